// Round 11
// baseline (245.337 us; speedup 1.0000x reference)
//
#include <hip/hip_runtime.h>
#include <math.h>

// ---------------- problem constants ----------------
constexpr int Bn  = 128;
constexpr int Kd  = 65536;    // magnitude dim (phase half of feats is zeros)
constexpr int F1  = 128;
constexpr int F2  = 64;
constexpr int NM  = 3;
constexpr int Qd  = 256;
constexpr int NCH = 512;      // split-K chunks for big GEMM
constexpr int KC  = 128;      // k per chunk
constexpr int MSZ = 256 * 256;

// Muon (growth) quintic Newton-Schulz coefficients
#define MA 3.4445f
#define MB (-4.7750f)
#define MC 2.0315f
// degree-9 convergent NS: x*(315 - 420y + 378y^2 - 180y^3 + 35y^4)/128, y=x^2
#define D9_0 (315.f / 128.f)
#define D9_1 (-420.f / 128.f)
#define D9_2 (378.f / 128.f)
#define D9_3 (-180.f / 128.f)
#define D9_4 (35.f / 128.f)

// ---------------- ws layout (float offsets) ----------------
constexpr size_t OFF_H1P  = 0;                                   // 512*128*128 floats
constexpr size_t OFF_H1   = OFF_H1P + (size_t)NCH * Bn * F1;
constexpr size_t OFF_SEL  = OFF_H1 + (size_t)Bn * F1;
constexpr size_t OFF_PART = OFF_SEL + 128;
constexpr size_t OFF_XA   = OFF_PART + 64;
constexpr size_t OFF_XB   = OFF_XA + (size_t)NM * MSZ;
constexpr size_t OFF_ACP  = OFF_XB + (size_t)NM * MSZ;           // u32: NM*128*256

// ---------------- f16 helpers (NS chain) ----------------
typedef __fp16 half2_t __attribute__((ext_vector_type(2)));
union HU { half2_t h; unsigned int u; };
__device__ __forceinline__ unsigned int pkh(float x, float y) {
  HU v; v.h = __builtin_amdgcn_cvt_pkrtz(x, y); return v.u;
}
__device__ __forceinline__ half2_t uh(unsigned int u) { HU v; v.u = u; return v.h; }

#if __has_builtin(__builtin_amdgcn_fdot2)
#define FDOT2(a, b, c) __builtin_amdgcn_fdot2((a), (b), (c), false)
#else
#define FDOT2(a, b, c) ((c) + (float)(a)[0] * (float)(b)[0] + (float)(a)[1] * (float)(b)[1])
#endif

// ---------------- bf16 helpers (MFMA GEMM) ----------------
typedef short bf16x8 __attribute__((ext_vector_type(8)));
typedef float f32x4 __attribute__((ext_vector_type(4)));
__device__ __forceinline__ unsigned short bh(float x) {   // RNE fp32 -> bf16
  unsigned int bx = __float_as_uint(x);
  return (unsigned short)((bx + 0x7FFFu + ((bx >> 16) & 1u)) >> 16);
}
__device__ __forceinline__ float bf(unsigned short h) {
  return __uint_as_float((unsigned int)h << 16);
}

// ---------------- K1: split-K magnitude GEMM via bf16-split MFMA ----------------
__global__ __launch_bounds__(256) void k_gemm1(const float* __restrict__ sp,
                                               const float* __restrict__ W1,
                                               float* __restrict__ h1p) {
  __shared__ short Ah[128][72];
  __shared__ short Al[128][72];
  __shared__ short Bh[128][72];
  __shared__ short Bl[128][72];
  const int t = threadIdx.x;
  const int w = t >> 6, l = t & 63;
  const int l15 = l & 15, lg = l >> 4;
  const int ch = blockIdx.x;
  const size_t k0 = (size_t)ch * KC;
  const int srow = t >> 4;
  const int skq  = (t & 15) * 4;

  f32x4 acc[2][8];
#pragma unroll
  for (int r = 0; r < 2; ++r)
#pragma unroll
    for (int c = 0; c < 8; ++c) acc[r][c] = (f32x4){0.f, 0.f, 0.f, 0.f};

#pragma unroll
  for (int sub = 0; sub < 2; ++sub) {
    __syncthreads();
    const size_t kb = k0 + sub * 64 + skq;
#pragma unroll
    for (int rep = 0; rep < 8; ++rep) {
      const int row = srow + rep * 16;
      const float4 av = *(const float4*)(sp + (size_t)row * Kd + kb);
      const float4 bv = *(const float4*)(W1 + (size_t)row * (2 * Kd) + kb);
      float va[4] = {fabsf(av.x), fabsf(av.y), fabsf(av.z), fabsf(av.w)};
      float vb[4] = {bv.x, bv.y, bv.z, bv.w};
      unsigned short ha[4], la[4], hb[4], lb[4];
#pragma unroll
      for (int e = 0; e < 4; ++e) {
        ha[e] = bh(va[e]); la[e] = bh(va[e] - bf(ha[e]));
        hb[e] = bh(vb[e]); lb[e] = bh(vb[e] - bf(hb[e]));
      }
      *(uint2*)&Ah[row][skq] = make_uint2((unsigned)ha[0] | ((unsigned)ha[1] << 16),
                                          (unsigned)ha[2] | ((unsigned)ha[3] << 16));
      *(uint2*)&Al[row][skq] = make_uint2((unsigned)la[0] | ((unsigned)la[1] << 16),
                                          (unsigned)la[2] | ((unsigned)la[3] << 16));
      *(uint2*)&Bh[row][skq] = make_uint2((unsigned)hb[0] | ((unsigned)hb[1] << 16),
                                          (unsigned)hb[2] | ((unsigned)hb[3] << 16));
      *(uint2*)&Bl[row][skq] = make_uint2((unsigned)lb[0] | ((unsigned)lb[1] << 16),
                                          (unsigned)lb[2] | ((unsigned)lb[3] << 16));
    }
    __syncthreads();
#pragma unroll
    for (int ks = 0; ks < 2; ++ks) {
      const int ko = ks * 32 + lg * 8;
      bf16x8 afh[2], afl[2];
#pragma unroll
      for (int r = 0; r < 2; ++r) {
        const int row = w * 32 + r * 16 + l15;
        afh[r] = *(const bf16x8*)&Ah[row][ko];
        afl[r] = *(const bf16x8*)&Al[row][ko];
      }
#pragma unroll
      for (int c = 0; c < 8; ++c) {
        const int col = c * 16 + l15;
        const bf16x8 bfh = *(const bf16x8*)&Bh[col][ko];
        const bf16x8 bfl = *(const bf16x8*)&Bl[col][ko];
#pragma unroll
        for (int r = 0; r < 2; ++r) {
          acc[r][c] = __builtin_amdgcn_mfma_f32_16x16x32_bf16(afh[r], bfh, acc[r][c], 0, 0, 0);
          acc[r][c] = __builtin_amdgcn_mfma_f32_16x16x32_bf16(afh[r], bfl, acc[r][c], 0, 0, 0);
          acc[r][c] = __builtin_amdgcn_mfma_f32_16x16x32_bf16(afl[r], bfh, acc[r][c], 0, 0, 0);
        }
      }
    }
  }

  float* outp = h1p + (size_t)ch * (Bn * F1);
#pragma unroll
  for (int r = 0; r < 2; ++r)
#pragma unroll
    for (int c = 0; c < 8; ++c) {
      const int col = c * 16 + l15;
#pragma unroll
      for (int reg = 0; reg < 4; ++reg) {
        const int row = w * 32 + r * 16 + lg * 4 + reg;
        outp[row * F1 + col] = acc[r][c][reg];
      }
    }
}

// ---------------- K1b: reduce partials + bias + relu (512 chunks) ----------------
__global__ __launch_bounds__(256) void k_red(const float* __restrict__ h1p,
                                             const float* __restrict__ b1,
                                             float* __restrict__ h1) {
  const int t = threadIdx.x;
  const int ol = t & 63;
  const int g = t >> 6;
  const int o = blockIdx.x * 64 + ol;
  double s = 0.0;
#pragma unroll 8
  for (int c = g * 128; c < g * 128 + 128; ++c)
    s += (double)h1p[(size_t)c * (Bn * F1) + o];
  __shared__ double red[4][64];
  red[g][ol] = s;
  __syncthreads();
  if (g == 0) {
    const double v = red[0][ol] + red[1][ol] + red[2][ol] + red[3][ol];
    const float r = (float)v + b1[o & 127];
    h1[o] = fmaxf(r, 0.f);
  }
}

// ---------------- K2: small MLP + syndrome + selection ----------------
__global__ __launch_bounds__(256) void k_mlp(const float* __restrict__ h1,
                                             const float* __restrict__ W2,
                                             const float* __restrict__ b2,
                                             const float* __restrict__ W3,
                                             const float* __restrict__ b3,
                                             int* __restrict__ sel) {
  const int t = threadIdx.x;
  const int b0 = blockIdx.x * 16;
  __shared__ float h2s[16 * 64];
  for (int o = t; o < 16 * 64; o += 256) {
    const int bl = o >> 6, j = o & 63;
    const float* hr = h1 + (b0 + bl) * F1;
    const float* wr = W2 + j * F1;
    float s = b2[j];
    for (int k = 0; k < F1; ++k) s += hr[k] * wr[k];
    h2s[o] = fmaxf(s, 0.f);
  }
  __syncthreads();
  if (t < 16) {
    const int b = b0 + t;
    float best = -1.f;
    int bi = 0;
    bool needed = false;
    for (int j = 0; j < 8; ++j) {
      double s = (double)b3[j];
      const float* wr = W3 + j * F2;
      for (int k = 0; k < F2; ++k) s += (double)h2s[t * F2 + k] * (double)wr[k];
      const float a = fabsf((float)s);
      if (a > 1e-4f) needed = true;
      if (a > best) { best = a; bi = j; }
    }
    sel[b] = needed ? (bi % NM) : -1;
  }
}

// ---------------- NS phase A: A = X^T X -> f16 colpk (symmetric 32x32 tiles) ----------------
__global__ __launch_bounds__(512) void k_pA(const float* __restrict__ Xs,
                                            unsigned int* __restrict__ Acp,
                                            float* __restrict__ part) {
  const int bid = blockIdx.x;
  const int m = bid / 36;
  int rem = bid % 36;
  int I = 0;
  while (rem >= 8 - I) { rem -= 8 - I; ++I; }
  const int J = I + rem;
  const float* Xm = Xs + (size_t)m * MSZ;
  unsigned int* Am = Acp + (size_t)m * (128 * 256);
  __shared__ float PI[32][260];
  __shared__ float PJb[32][260];
  __shared__ float red[7][64][17];
  __shared__ float tr8[8];
  float (*PJ)[260] = (I == J) ? PI : PJb;
  const int t = threadIdx.x;

#pragma unroll
  for (int it = 0; it < 4; ++it) {
    const int task = it * 512 + t;
    const int k = task >> 3, c4 = task & 7;
    const float4 vI = *(const float4*)&Xm[k * 256 + I * 32 + c4 * 4];
#pragma unroll
    for (int e = 0; e < 4; ++e) PI[c4 * 4 + e][k] = (&vI.x)[e];
    if (I != J) {
      const float4 vJ = *(const float4*)&Xm[k * 256 + J * 32 + c4 * 4];
#pragma unroll
      for (int e = 0; e < 4; ++e) PJb[c4 * 4 + e][k] = (&vJ.x)[e];
    }
  }
  __syncthreads();

  const int h = t >> 6, u = t & 63, ur = u >> 3, uc = u & 7;
  float a[4][4];
#pragma unroll
  for (int i = 0; i < 4; ++i)
#pragma unroll
    for (int j = 0; j < 4; ++j) a[i][j] = 0.f;

  const int kb = h * 32;
#pragma unroll 8
  for (int kk = 0; kk < 32; ++kk) {
    const int k = kb + kk;
    float xi[4], xj[4];
#pragma unroll
    for (int i = 0; i < 4; ++i) xi[i] = PI[ur * 4 + i][k];
#pragma unroll
    for (int j = 0; j < 4; ++j) xj[j] = PJ[uc * 4 + j][k];
#pragma unroll
    for (int i = 0; i < 4; ++i)
#pragma unroll
      for (int j = 0; j < 4; ++j) a[i][j] += xi[i] * xj[j];
  }
  if (h) {
    float* rr = &red[h - 1][u][0];
#pragma unroll
    for (int i = 0; i < 4; ++i)
#pragma unroll
      for (int j = 0; j < 4; ++j) rr[i * 4 + j] = a[i][j];
  }
  __syncthreads();
  if (h == 0) {
#pragma unroll
    for (int i = 0; i < 4; ++i)
#pragma unroll
      for (int j = 0; j < 4; ++j) {
        float s = a[i][j];
#pragma unroll
        for (int q = 0; q < 7; ++q) s += red[q][u][i * 4 + j];
        a[i][j] = s;
      }
    const int gr = I * 32 + ur * 4, gc = J * 32 + uc * 4;
    {
      const int kp = gr >> 1;
      *(uint4*)&Am[kp * 256 + gc] =
          make_uint4(pkh(a[0][0], a[1][0]), pkh(a[0][1], a[1][1]),
                     pkh(a[0][2], a[1][2]), pkh(a[0][3], a[1][3]));
      *(uint4*)&Am[(kp + 1) * 256 + gc] =
          make_uint4(pkh(a[2][0], a[3][0]), pkh(a[2][1], a[3][1]),
                     pkh(a[2][2], a[3][2]), pkh(a[2][3], a[3][3]));
    }
    if (I != J) {
      const int kp = gc >> 1;
      *(uint4*)&Am[kp * 256 + gr] =
          make_uint4(pkh(a[0][0], a[0][1]), pkh(a[1][0], a[1][1]),
                     pkh(a[2][0], a[2][1]), pkh(a[3][0], a[3][1]));
      *(uint4*)&Am[(kp + 1) * 256 + gr] =
          make_uint4(pkh(a[0][2], a[0][3]), pkh(a[1][2], a[1][3]),
                     pkh(a[2][2], a[2][3]), pkh(a[3][2], a[3][3]));
    } else if (ur == uc) {
      tr8[ur] = a[0][0] + a[1][1] + a[2][2] + a[3][3];
    }
  }
  if (I == J) {
    __syncthreads();
    if (t == 0) {
      float s = 0.f;
#pragma unroll
      for (int q = 0; q < 8; ++q) s += tr8[q];
      part[m * 8 + I] = s;
    }
  }
}

// ---------------- pass helper: r = (src · A) * is2, f32 on h==0 threads ----------------
// caller must pack/combine on h==0 then __syncthreads() before next pass.
__device__ __forceinline__ void passA(const unsigned int (*__restrict__ src)[132],
                                      const uint4* __restrict__ A4,
                                      float (*__restrict__ red)[64][17],
                                      const int h, const int u, const float is2,
                                      float r[4][4]) {
  const int kp0 = h * 16;
  float acc[4][4];
#pragma unroll
  for (int i = 0; i < 4; ++i)
#pragma unroll
    for (int j = 0; j < 4; ++j) acc[i][j] = 0.f;
#pragma unroll 8
  for (int kk = 0; kk < 16; ++kk) {
    const int kp = kp0 + kk;
    const uint4 aw = A4[kp * 64 + u];
    const half2_t b0 = uh(aw.x), b1 = uh(aw.y), b2 = uh(aw.z), b3 = uh(aw.w);
#pragma unroll
    for (int rr4 = 0; rr4 < 4; ++rr4) {
      const half2_t xp = uh(src[rr4][kp]);
      acc[rr4][0] = FDOT2(xp, b0, acc[rr4][0]);
      acc[rr4][1] = FDOT2(xp, b1, acc[rr4][1]);
      acc[rr4][2] = FDOT2(xp, b2, acc[rr4][2]);
      acc[rr4][3] = FDOT2(xp, b3, acc[rr4][3]);
    }
  }
  if (h) {
    float* rr = &red[h - 1][u][0];
#pragma unroll
    for (int i = 0; i < 4; ++i)
#pragma unroll
      for (int j = 0; j < 4; ++j) rr[i * 4 + j] = acc[i][j];
  }
  __syncthreads();
  if (h == 0) {
#pragma unroll
    for (int i = 0; i < 4; ++i)
#pragma unroll
      for (int j = 0; j < 4; ++j) {
        float s = acc[i][j];
#pragma unroll
        for (int q = 0; q < 7; ++q) s += red[q][u][i * 4 + j];
        r[i][j] = s * is2;
      }
  }
}

// unpack this thread's 4 cols of row i from a packed strip buffer
__device__ __forceinline__ void up4(const unsigned int (*__restrict__ buf)[132],
                                    const int i, const int u, float v[4]) {
  const half2_t p0 = uh(buf[i][2 * u]), p1 = uh(buf[i][2 * u + 1]);
  v[0] = (float)p0[0]; v[1] = (float)p0[1]; v[2] = (float)p1[0]; v[3] = (float)p1[1];
}

// ---------------- NS phase B12: TWO Muon iterations in one dispatch ----------------
// X'' = X·p(A)·p(p(A)^2 A) evaluated factored as 12 strip·A passes.
// first=1: X scaled by 1/s at pack, every A-pass result scaled by 1/s^2.
__global__ __launch_bounds__(512) void k_pB12(const float* __restrict__ Xs,
                                              const unsigned int* __restrict__ Acp,
                                              const float* __restrict__ part,
                                              float* __restrict__ Xn,
                                              const int first) {
  const int m = blockIdx.x >> 6, g = blockIdx.x & 63, i0 = g * 4;
  const float* Xm = Xs + (size_t)m * MSZ;
  const uint4* A4 = (const uint4*)(Acp + (size_t)m * (128 * 256));
  float* Xo = Xn + (size_t)m * MSZ;
  const int t = threadIdx.x, h = t >> 6, u = t & 63;
  __shared__ unsigned int b0s[4][132], b1s[4][132], b2s[4][132], b3s[4][132];
  __shared__ float red[7][64][17];

  float is = 1.f, is2 = 1.f;
  if (first) {
    float tr = 0.f;
#pragma unroll
    for (int q = 0; q < 8; ++q) tr += part[m * 8 + q];
    const float s = 0.15f * sqrtf(tr);   // 1.2 * 2||C||_F/sqrt(256)
    is = 1.f / s; is2 = is * is;
  }

  if (t < 256) {  // pack X*is into b0s
    const int r = t >> 6, c16 = t & 63;
    float4 v = *(const float4*)&Xm[(i0 + r) * 256 + c16 * 4];
    v.x *= is; v.y *= is; v.z *= is; v.w *= is;
    b0s[r][2 * c16]     = pkh(v.x, v.y);
    b0s[r][2 * c16 + 1] = pkh(v.z, v.w);
  }
  __syncthreads();

  float r1[4][4], r2[4][4], out[4][4], cmb[4][4];

#define PACK(DST, V)                                        \
  if (h == 0) {                                             \
    _Pragma("unroll")                                       \
    for (int i = 0; i < 4; ++i) {                           \
      DST[i][2 * u]     = pkh(V[i][0], V[i][1]);            \
      DST[i][2 * u + 1] = pkh(V[i][2], V[i][3]);            \
    }                                                       \
  }                                                         \
  __syncthreads();

#define COMBINE(SBUF, TBUF, R2, OUTV)                       \
  if (h == 0) {                                             \
    _Pragma("unroll")                                       \
    for (int i = 0; i < 4; ++i) {                           \
      float sv[4], tv[4];                                   \
      up4(SBUF, i, u, sv);                                  \
      up4(TBUF, i, u, tv);                                  \
      _Pragma("unroll")                                     \
      for (int j = 0; j < 4; ++j)                           \
        OUTV[i][j] = MA * sv[j] + MB * tv[j] + MC * R2[i][j]; \
    }                                                       \
  }

  // ---- T = mulP(X): P1, P2 ----
  passA(b0s, A4, red, h, u, is2, r1); PACK(b1s, r1);
  passA(b1s, A4, red, h, u, is2, r2);
  COMBINE(b0s, b1s, r2, cmb);                 // T = a·X + b·XA + c·XAA
  if (h == 0) {
#pragma unroll
    for (int i = 0; i < 4; ++i)
#pragma unroll
      for (int j = 0; j < 4; ++j) out[i][j] = MA * cmb[i][j];
  }
  PACK(b2s, cmb);                             // T in b2s

  // ---- M1 = mulP(T): P3, P4 ----
  passA(b2s, A4, red, h, u, is2, r1); PACK(b1s, r1);
  passA(b1s, A4, red, h, u, is2, r2);
  COMBINE(b2s, b1s, r2, cmb); PACK(b3s, cmb); // M1 in b3s

  // ---- M2 = mulP(M1): P5, P6 ----
  passA(b3s, A4, red, h, u, is2, r1); PACK(b1s, r1);
  passA(b1s, A4, red, h, u, is2, r2);
  COMBINE(b3s, b1s, r2, cmb); PACK(b2s, cmb); // M2 in b2s (T dead)

  // ---- U = M2·A: P7 ----
  passA(b2s, A4, red, h, u, is2, r1);
  if (h == 0) {
#pragma unroll
    for (int i = 0; i < 4; ++i)
#pragma unroll
      for (int j = 0; j < 4; ++j) out[i][j] += MB * r1[i][j];
  }
  PACK(b3s, r1);                              // U in b3s

  // ---- M3 = mulP(U): P8, P9 ----
  passA(b3s, A4, red, h, u, is2, r1); PACK(b1s, r1);
  passA(b1s, A4, red, h, u, is2, r2);
  COMBINE(b3s, b1s, r2, cmb); PACK(b2s, cmb); // M3 in b2s

  // ---- M4 = mulP(M3): P10, P11 ----
  passA(b2s, A4, red, h, u, is2, r1); PACK(b1s, r1);
  passA(b1s, A4, red, h, u, is2, r2);
  COMBINE(b2s, b1s, r2, cmb); PACK(b3s, cmb); // M4 in b3s

  // ---- V = M4·A: P12, final combine ----
  passA(b3s, A4, red, h, u, is2, r1);
  if (h == 0) {
#pragma unroll
    for (int i = 0; i < 4; ++i) {
#pragma unroll
      for (int j = 0; j < 4; ++j) out[i][j] += MC * r1[i][j];
      *(float4*)&Xo[(i0 + i) * 256 + u * 4] =
          make_float4(out[i][0], out[i][1], out[i][2], out[i][3]);
    }
  }
#undef PACK
#undef COMBINE
}

// ---------------- NS phase B9 (degree-9 convergent): X' = sum_{p=0..4} D9_p * X A^p ----------------
__global__ __launch_bounds__(512) void k_pB9(const float* __restrict__ Xs,
                                             const unsigned int* __restrict__ Acp,
                                             float* __restrict__ Xn) {
  const int m = blockIdx.x >> 6, g = blockIdx.x & 63, i0 = g * 4;
  const float* Xm = Xs + (size_t)m * MSZ;
  const uint4* A4 = (const uint4*)(Acp + (size_t)m * (128 * 256));
  float* Xo = Xn + (size_t)m * MSZ;
  const int t = threadIdx.x, h = t >> 6, u = t & 63;
  __shared__ float xs[4][260];
  __shared__ unsigned int buf0[4][132];
  __shared__ unsigned int buf1[4][132];
  __shared__ float red[7][64][17];

  if (t < 256) {
    const int r = t >> 6, c16 = t & 63;
    const float4 v = *(const float4*)&Xm[(i0 + r) * 256 + c16 * 4];
    *(float4*)&xs[r][c16 * 4] = v;
    buf0[r][2 * c16]     = pkh(v.x, v.y);
    buf0[r][2 * c16 + 1] = pkh(v.z, v.w);
  }
  __syncthreads();

  float out[4][4];
  if (h == 0) {
#pragma unroll
    for (int i = 0; i < 4; ++i)
#pragma unroll
      for (int j = 0; j < 4; ++j) out[i][j] = D9_0 * xs[i][u * 4 + j];
  }

#pragma unroll
  for (int p = 0; p < 4; ++p) {
    const float cp = (p == 0) ? D9_1 : (p == 1) ? D9_2 : (p == 2) ? D9_3 : D9_4;
    unsigned int (*src)[132] = (p & 1) ? buf1 : buf0;
    unsigned int (*dst)[132] = (p & 1) ? buf0 : buf1;

    float r1[4][4];
    passA(src, A4, red, h, u, 1.f, r1);
    if (h == 0) {
#pragma unroll
      for (int i = 0; i < 4; ++i) {
#pragma unroll
        for (int j = 0; j < 4; ++j) out[i][j] += cp * r1[i][j];
        if (p < 3) {
          dst[i][2 * u]     = pkh(r1[i][0], r1[i][1]);
          dst[i][2 * u + 1] = pkh(r1[i][2], r1[i][3]);
        }
      }
    }
    __syncthreads();
  }

  if (h == 0) {
#pragma unroll
    for (int i = 0; i < 4; ++i)
      *(float4*)&Xo[(i0 + i) * 256 + u * 4] =
          make_float4(out[i][0], out[i][1], out[i][2], out[i][3]);
  }
}

// ---------------- K4: output assembly ----------------
__global__ __launch_bounds__(256) void k_out(const float* __restrict__ sp,
                                             const float* __restrict__ P,
                                             const int* __restrict__ sel,
                                             float* __restrict__ out) {
  const int t = threadIdx.x;
  if (blockIdx.x < 128) {
    const int b = blockIdx.x;
    __shared__ float hd[256];
    hd[t] = sp[(size_t)b * Kd + t];
    __syncthreads();
    const int s = sel[b];
    if (s < 0) {
      out[(size_t)b * Kd + t] = hd[t];
    } else {
      const float4* prow = (const float4*)(P + (size_t)s * MSZ + t * 256);
      float acc = 0.f;
#pragma unroll 8
      for (int j4 = 0; j4 < 64; ++j4) {
        const float4 p = prow[j4];
        acc += p.x * hd[4 * j4 + 0] + p.y * hd[4 * j4 + 1] +
               p.z * hd[4 * j4 + 2] + p.w * hd[4 * j4 + 3];
      }
      out[(size_t)b * Kd + t] = hd[t] + 0.1f * acc;
    }
  } else {
    const int ci = blockIdx.x - 128;
    const float4* in4 = (const float4*)sp;
    float4* out4 = (float4*)out;
    const int total = Bn * (Kd / 4);
    for (int i = ci * 256 + t; i < total; i += 2048 * 256) {
      const int pos = i & ((Kd / 4) - 1);
      if (pos >= Qd / 4) out4[i] = in4[i];
    }
  }
}

// ---------------- host ----------------
extern "C" void kernel_launch(void* const* d_in, const int* in_sizes, int n_in,
                              void* d_out, int out_size, void* d_ws, size_t ws_size,
                              hipStream_t stream) {
  (void)in_sizes; (void)n_in; (void)out_size; (void)ws_size;
  const float* sp = (const float*)d_in[0];
  const float* W1 = (const float*)d_in[1];
  const float* b1 = (const float*)d_in[2];
  const float* W2 = (const float*)d_in[3];
  const float* b2 = (const float*)d_in[4];
  const float* W3 = (const float*)d_in[5];
  const float* b3 = (const float*)d_in[6];
  const float* ops = (const float*)d_in[7];
  float* out = (float*)d_out;
  float* ws = (float*)d_ws;

  float* h1p  = ws + OFF_H1P;
  float* h1   = ws + OFF_H1;
  int*   sel  = (int*)(ws + OFF_SEL);
  float* part = ws + OFF_PART;
  float* Xa   = ws + OFF_XA;
  float* Xb   = ws + OFF_XB;
  unsigned int* Acp = (unsigned int*)(ws + OFF_ACP);

  k_gemm1<<<NCH, 256, 0, stream>>>(sp, W1, h1p);
  k_red<<<256, 256, 0, stream>>>(h1p, b1, h1);
  k_mlp<<<8, 256, 0, stream>>>(h1, W2, b2, W3, b3, sel);

  // 8 Muon iterations as 4 doubles, then degree-9 convergent
  k_pA<<<NM * 36, 512, 0, stream>>>(ops, Acp, part);
  k_pB12<<<192, 512, 0, stream>>>(ops, Acp, part, Xa, 1);   // iters 0-1

  float* X = Xa;
  float* Xn = Xb;
  for (int d = 0; d < 3; ++d) {                             // iters 2-3, 4-5, 6-7
    k_pA<<<NM * 36, 512, 0, stream>>>(X, Acp, part);
    k_pB12<<<192, 512, 0, stream>>>(X, Acp, part, Xn, 0);
    float* tmp = X; X = Xn; Xn = tmp;
  }
  k_pA<<<NM * 36, 512, 0, stream>>>(X, Acp, part);
  k_pB9<<<192, 512, 0, stream>>>(X, Acp, Xn);
  X = Xn;

  k_out<<<128 + 2048, 256, 0, stream>>>(sp, X, sel, out);
}